// Round 1
// baseline (17183.408 us; speedup 1.0000x reference)
//
#include <hip/hip_runtime.h>

#define V_N   200000
#define E_N   600000
#define FEAT  960
#define HDIM  128
#define NREST 7
#define NSCAN 196   // ceil(V_N/1024)

// ---------------------------------------------------------------------------
// Backbone: x[v][n] = relu( sum_k img[v][k] * W[n][k] + b[n] ),  K=960, N=128
// Thread per vertex; acc[128] in VGPRs; weight loads are wave-uniform (scalar).
// ---------------------------------------------------------------------------
__global__ __launch_bounds__(256) void backbone_kernel(
    const float* __restrict__ img, const float* __restrict__ W,
    const float* __restrict__ b, float* __restrict__ x)
{
    int v = blockIdx.x * blockDim.x + threadIdx.x;
    if (v >= V_N) return;
    float acc[HDIM];
    #pragma unroll
    for (int n = 0; n < HDIM; ++n) acc[n] = b[n];
    const float* xin = img + (size_t)v * FEAT;
    #pragma unroll 1
    for (int k0 = 0; k0 < FEAT; k0 += 8) {
        float4 a0 = *(const float4*)(xin + k0);
        float4 a1 = *(const float4*)(xin + k0 + 4);
        float xc[8] = {a0.x, a0.y, a0.z, a0.w, a1.x, a1.y, a1.z, a1.w};
        #pragma unroll
        for (int n = 0; n < HDIM; ++n) {
            const float* wr = W + (size_t)n * FEAT + k0;
            #pragma unroll
            for (int kk = 0; kk < 8; ++kk)
                acc[n] += xc[kk] * wr[kk];
        }
    }
    float* xo = x + (size_t)v * HDIM;
    #pragma unroll
    for (int n = 0; n < HDIM; ++n) xo[n] = fmaxf(acc[n], 0.f);
}

// ---------------------------------------------------------------------------
// GraphConv GEMM: y0 = x@W0.T + b0 ; y1 = x@W1.T + b1   (K=128 (+3 verts))
// y packed [V][256]: cols 0..127 = y0, 128..255 = y1.
// ---------------------------------------------------------------------------
template<int KSTRIDE, bool HASV>
__global__ __launch_bounds__(256) void gconv_gemm_kernel(
    const float* __restrict__ x, const float* __restrict__ verts,
    const float* __restrict__ W0, const float* __restrict__ b0,
    const float* __restrict__ W1, const float* __restrict__ b1,
    float* __restrict__ y)
{
    int v = blockIdx.x * blockDim.x + threadIdx.x;
    if (v >= V_N) return;
    float xr[HDIM];
    const float* xin = x + (size_t)v * HDIM;
    #pragma unroll
    for (int k0 = 0; k0 < HDIM; k0 += 4) {
        float4 t = *(const float4*)(xin + k0);
        xr[k0] = t.x; xr[k0+1] = t.y; xr[k0+2] = t.z; xr[k0+3] = t.w;
    }
    float v0 = 0.f, v1 = 0.f, v2 = 0.f;
    if (HASV) { v0 = verts[3*v]; v1 = verts[3*v+1]; v2 = verts[3*v+2]; }
    float* yo = y + (size_t)v * 256;
    #pragma unroll 1
    for (int n = 0; n < HDIM; ++n) {
        float aA = b0[n], aB = b1[n];
        const float* w0 = W0 + n * KSTRIDE;
        const float* w1 = W1 + n * KSTRIDE;
        #pragma unroll
        for (int k = 0; k < HDIM; ++k) {
            aA += xr[k] * w0[k];
            aB += xr[k] * w1[k];
        }
        if (HASV) {
            aA += v0*w0[128] + v1*w0[129] + v2*w0[130];
            aB += v0*w1[128] + v1*w1[129] + v2*w1[130];
        }
        yo[n]       = aA;
        yo[128 + n] = aB;
    }
}

// ---------------------------------------------------------------------------
// Aggregation: x[v] = relu( y0[v] + sum_{u in adj(v)} y1[u] )
// One wave per vertex, 2 floats per lane.
// ---------------------------------------------------------------------------
__global__ __launch_bounds__(256) void agg_kernel(
    const float* __restrict__ y, const int* __restrict__ rowp,
    const int* __restrict__ col, float* __restrict__ x)
{
    int wid  = (blockIdx.x * blockDim.x + threadIdx.x) >> 6;
    int lane = threadIdx.x & 63;
    if (wid >= V_N) return;
    const float2* y0 = (const float2*)(y + (size_t)wid * 256);
    float2 acc = y0[lane];
    int s = rowp[wid], e = rowp[wid + 1];
    for (int p = s; p < e; ++p) {
        int u = col[p];
        const float2* y1 = (const float2*)(y + (size_t)u * 256 + 128);
        float2 t = y1[lane];
        acc.x += t.x; acc.y += t.y;
    }
    float2* xo = (float2*)(x + (size_t)wid * HDIM);
    xo[lane] = make_float2(fmaxf(acc.x, 0.f), fmaxf(acc.y, 0.f));
}

// ---------------------------------------------------------------------------
// Final projection: out[v] = x[v] @ vo_W.T + vo_b   (3 outputs)
// ---------------------------------------------------------------------------
__global__ __launch_bounds__(256) void vout_kernel(
    const float* __restrict__ x, const float* __restrict__ W,
    const float* __restrict__ b, float* __restrict__ out)
{
    int v = blockIdx.x * blockDim.x + threadIdx.x;
    if (v >= V_N) return;
    const float* xin = x + (size_t)v * HDIM;
    float a0 = b[0], a1 = b[1], a2 = b[2];
    #pragma unroll
    for (int k = 0; k < HDIM; ++k) {
        float xv = xin[k];
        a0 += xv * W[k];
        a1 += xv * W[HDIM + k];
        a2 += xv * W[2*HDIM + k];
    }
    out[3*v]   = a0;
    out[3*v+1] = a1;
    out[3*v+2] = a2;
}

// ------------------------- CSR construction -------------------------------
__global__ void deg_count_kernel(const int* __restrict__ edges, int* __restrict__ deg)
{
    int e = blockIdx.x * blockDim.x + threadIdx.x;
    if (e >= E_N) return;
    int i = edges[2*e], j = edges[2*e+1];
    atomicAdd(&deg[i], 1);
    atomicAdd(&deg[j], 1);
}

__global__ __launch_bounds__(1024) void scan_block_kernel(
    const int* __restrict__ deg, int* __restrict__ excl, int* __restrict__ bsum)
{
    __shared__ int sdata[1024];
    int t = threadIdx.x;
    int base = blockIdx.x * 1024;
    int val = (base + t < V_N) ? deg[base + t] : 0;
    sdata[t] = val; __syncthreads();
    for (int off = 1; off < 1024; off <<= 1) {
        int tmp = (t >= off) ? sdata[t - off] : 0;
        __syncthreads();
        sdata[t] += tmp;
        __syncthreads();
    }
    if (base + t < V_N) excl[base + t] = sdata[t] - val;
    if (t == 1023) bsum[blockIdx.x] = sdata[1023];
}

__global__ __launch_bounds__(256) void scan_bsum_kernel(
    const int* __restrict__ bsum, int* __restrict__ boff)
{
    __shared__ int sdata[256];
    int t = threadIdx.x;
    int val = (t < NSCAN) ? bsum[t] : 0;
    sdata[t] = val; __syncthreads();
    for (int off = 1; off < 256; off <<= 1) {
        int tmp = (t >= off) ? sdata[t - off] : 0;
        __syncthreads();
        sdata[t] += tmp;
        __syncthreads();
    }
    if (t < NSCAN) boff[t] = sdata[t] - val;
    if (t == 255) boff[NSCAN] = sdata[255];   // total = 2E
}

__global__ void scan_add_kernel(const int* __restrict__ boff,
                                int* __restrict__ rowp, int* __restrict__ cur)
{
    int i = blockIdx.x * blockDim.x + threadIdx.x;
    if (i < V_N) {
        int r = rowp[i] + boff[i >> 10];
        rowp[i] = r;
        cur[i] = r;
    } else if (i == V_N) {
        rowp[V_N] = boff[NSCAN];
    }
}

__global__ void fill_kernel(const int* __restrict__ edges,
                            int* __restrict__ cur, int* __restrict__ col)
{
    int e = blockIdx.x * blockDim.x + threadIdx.x;
    if (e >= E_N) return;
    int i = edges[2*e], j = edges[2*e+1];
    col[atomicAdd(&cur[i], 1)] = j;
    col[atomicAdd(&cur[j], 1)] = i;
}

// ---------------------------------------------------------------------------
extern "C" void kernel_launch(void* const* d_in, const int* in_sizes, int n_in,
                              void* d_out, int out_size, void* d_ws, size_t ws_size,
                              hipStream_t stream)
{
    const float* img   = (const float*)d_in[0];
    const float* verts = (const float*)d_in[1];
    const int*   edges = (const int*)  d_in[2];
    const float* bnW   = (const float*)d_in[3];
    const float* bnb   = (const float*)d_in[4];
    const float* g0W0  = (const float*)d_in[5];
    const float* g0b0  = (const float*)d_in[6];
    const float* g0W1  = (const float*)d_in[7];
    const float* g0b1  = (const float*)d_in[8];
    const float* gW0   = (const float*)d_in[9];
    const float* gb0   = (const float*)d_in[10];
    const float* gW1   = (const float*)d_in[11];
    const float* gb1   = (const float*)d_in[12];
    const float* voW   = (const float*)d_in[13];
    const float* vob   = (const float*)d_in[14];
    float* out = (float*)d_out;

    // workspace layout
    float* xbuf = (float*)d_ws;                       // V*128 f
    float* ybuf = xbuf + (size_t)V_N * HDIM;          // V*256 f
    int*   deg  = (int*)(ybuf + (size_t)V_N * 256);   // V
    int*   rowp = deg  + V_N;                         // V+1
    int*   cur  = rowp + V_N + 1;                     // V
    int*   bsum = cur  + V_N;                         // 256
    int*   boff = bsum + 256;                         // 257
    int*   col  = boff + 257;                         // 2E

    // ---- CSR build (per call; deterministic work) ----
    hipMemsetAsync(deg, 0, V_N * sizeof(int), stream);
    deg_count_kernel<<<(E_N + 255) / 256, 256, 0, stream>>>(edges, deg);
    scan_block_kernel<<<NSCAN, 1024, 0, stream>>>(deg, rowp, bsum);
    scan_bsum_kernel<<<1, 256, 0, stream>>>(bsum, boff);
    scan_add_kernel<<<(V_N + 256) / 256, 256, 0, stream>>>(boff, rowp, cur);
    fill_kernel<<<(E_N + 255) / 256, 256, 0, stream>>>(edges, cur, col);

    // ---- backbone ----
    backbone_kernel<<<(V_N + 255) / 256, 256, 0, stream>>>(img, bnW, bnb, xbuf);

    // ---- graph conv layer 0 (K = 131 via verts epilogue) ----
    gconv_gemm_kernel<131, true><<<(V_N + 255) / 256, 256, 0, stream>>>(
        xbuf, verts, g0W0, g0b0, g0W1, g0b1, ybuf);
    agg_kernel<<<(V_N * 64 + 255) / 256, 256, 0, stream>>>(ybuf, rowp, col, xbuf);

    // ---- graph conv layers 1..7 ----
    for (int l = 0; l < NREST; ++l) {
        gconv_gemm_kernel<128, false><<<(V_N + 255) / 256, 256, 0, stream>>>(
            xbuf, nullptr,
            gW0 + (size_t)l * HDIM * HDIM, gb0 + (size_t)l * HDIM,
            gW1 + (size_t)l * HDIM * HDIM, gb1 + (size_t)l * HDIM, ybuf);
        agg_kernel<<<(V_N * 64 + 255) / 256, 256, 0, stream>>>(ybuf, rowp, col, xbuf);
    }

    // ---- final projection ----
    vout_kernel<<<(V_N + 255) / 256, 256, 0, stream>>>(xbuf, voW, vob, out);
}

// Round 2
// 1698.367 us; speedup vs baseline: 10.1176x; 10.1176x over previous
//
#include <hip/hip_runtime.h>

#define V_N   200000
#define E_N   600000
#define FEAT  960
#define HDIM  128
#define NREST 7
#define NSCAN 196   // ceil(V_N/1024)

typedef __attribute__((ext_vector_type(8))) short bf16x8;
typedef __attribute__((ext_vector_type(4))) float f32x4;

__device__ __forceinline__ unsigned short f2bf(float f) {
    unsigned u = __builtin_bit_cast(unsigned, f);
    unsigned r = (u + 0x7FFFu + ((u >> 16) & 1u)) >> 16;
    return (unsigned short)r;
}
__device__ __forceinline__ float bf2f(unsigned h) {
    unsigned u = h << 16;
    return __builtin_bit_cast(float, u);
}

// ---------------------------------------------------------------------------
// MFMA GEMM:  C[m][n] = relu?( sum_k A[m][k] * B[n][k] + bias[n] )
// BM=BN=128, BK=64. 256 threads = 4 waves in 2x2; each wave 64x64 (4x4 frags).
// A: fp32 (A_F32) converted inline, or bf16. B: bf16, row-major [N][K].
// LDS XOR-swizzle (elem ^ ((row&7)<<3)) on both write and read.
// ---------------------------------------------------------------------------
template<int KT, bool A_F32, bool RELU>
__global__ __launch_bounds__(256) void mfma_gemm_kernel(
    const void* __restrict__ Av, int lda,
    const short* __restrict__ B, int ldb,
    const float* __restrict__ bias,
    short* __restrict__ C, int ldc)
{
    __shared__ short As[128 * 64];
    __shared__ short Bs[128 * 64];
    const int tid = threadIdx.x;
    const int bm0 = blockIdx.x * 128;
    const int bn0 = blockIdx.y * 128;
    const int wid = tid >> 6, lane = tid & 63;
    const int wm = wid >> 1, wn = wid & 1;

    // bias preloaded into accumulator (C col = lane&15 + n*16 + wn*64)
    f32x4 acc[4][4];
    #pragma unroll
    for (int n = 0; n < 4; ++n) {
        float bv = bias[bn0 + wn * 64 + n * 16 + (lane & 15)];
        #pragma unroll
        for (int m = 0; m < 4; ++m)
            acc[m][n] = (f32x4){bv, bv, bv, bv};
    }

    for (int it = 0; it < KT; ++it) {
        const int k0 = it * 64;
        __syncthreads();
        // ---- stage A tile [128][64] ----
        if constexpr (A_F32) {
            const float* A = (const float*)Av;
            #pragma unroll
            for (int i = 0; i < 8; ++i) {
                int c = i * 256 + tid;          // 2048 float4 chunks
                int row = c >> 4, c4 = c & 15;
                int grow = bm0 + row; if (grow >= V_N) grow = V_N - 1;
                float4 t = *(const float4*)(A + (size_t)grow * lda + k0 + c4 * 4);
                unsigned lo = (unsigned)f2bf(t.x) | ((unsigned)f2bf(t.y) << 16);
                unsigned hi = (unsigned)f2bf(t.z) | ((unsigned)f2bf(t.w) << 16);
                int e = (row * 64 + c4 * 4) ^ ((row & 7) << 3);
                *(uint2*)&As[e] = make_uint2(lo, hi);
            }
        } else {
            const short* A = (const short*)Av;
            #pragma unroll
            for (int i = 0; i < 4; ++i) {
                int c = i * 256 + tid;          // 1024 chunks of 8 bf16
                int row = c >> 3, c8 = c & 7;
                int grow = bm0 + row; if (grow >= V_N) grow = V_N - 1;
                float4 t = *(const float4*)(A + (size_t)grow * lda + k0 + c8 * 8);
                int e = (row * 64 + c8 * 8) ^ ((row & 7) << 3);
                *(float4*)&As[e] = t;
            }
        }
        // ---- stage B tile [128][64] ----
        #pragma unroll
        for (int i = 0; i < 4; ++i) {
            int c = i * 256 + tid;
            int row = c >> 3, c8 = c & 7;
            float4 t = *(const float4*)(B + (size_t)(bn0 + row) * ldb + k0 + c8 * 8);
            int e = (row * 64 + c8 * 8) ^ ((row & 7) << 3);
            *(float4*)&Bs[e] = t;
        }
        __syncthreads();
        // ---- compute: 2 k-steps of 32 ----
        #pragma unroll
        for (int kk = 0; kk < 2; ++kk) {
            bf16x8 a[4], b[4];
            #pragma unroll
            for (int m = 0; m < 4; ++m) {
                int row = wm * 64 + m * 16 + (lane & 15);
                int e = (row * 64 + kk * 32 + (lane >> 4) * 8) ^ ((row & 7) << 3);
                a[m] = *(const bf16x8*)&As[e];
            }
            #pragma unroll
            for (int n = 0; n < 4; ++n) {
                int row = wn * 64 + n * 16 + (lane & 15);
                int e = (row * 64 + kk * 32 + (lane >> 4) * 8) ^ ((row & 7) << 3);
                b[n] = *(const bf16x8*)&Bs[e];
            }
            #pragma unroll
            for (int m = 0; m < 4; ++m)
                #pragma unroll
                for (int n = 0; n < 4; ++n)
                    acc[m][n] = __builtin_amdgcn_mfma_f32_16x16x32_bf16(
                        a[m], b[n], acc[m][n], 0, 0, 0);
        }
    }

    // ---- epilogue: relu?, cvt bf16, store ----
    #pragma unroll
    for (int m = 0; m < 4; ++m) {
        int rbase = bm0 + wm * 64 + m * 16 + (lane >> 4) * 4;
        #pragma unroll
        for (int j = 0; j < 4; ++j) {
            int grow = rbase + j;
            if (grow < V_N) {
                #pragma unroll
                for (int n = 0; n < 4; ++n) {
                    float v = acc[m][n][j];
                    if (RELU) v = fmaxf(v, 0.f);
                    C[(size_t)grow * ldc + bn0 + wn * 64 + n * 16 + (lane & 15)] =
                        (short)f2bf(v);
                }
            }
        }
    }
}

// ---------------------------------------------------------------------------
// Aggregation: x[v] = relu( y0[v] + sum_{u in adj(v)} y1[u] ), all bf16 I/O.
// One wave per vertex, 2 bf16 per lane (uint loads).
// ---------------------------------------------------------------------------
__global__ __launch_bounds__(256) void agg_kernel(
    const short* __restrict__ y, const int* __restrict__ rowp,
    const int* __restrict__ col, short* __restrict__ x)
{
    int wid  = (blockIdx.x * blockDim.x + threadIdx.x) >> 6;
    int lane = threadIdx.x & 63;
    if (wid >= V_N) return;
    unsigned p0 = *(const unsigned*)(y + (size_t)wid * 256 + lane * 2);
    float ax = bf2f(p0 & 0xffffu), ay = bf2f(p0 >> 16);
    int s = rowp[wid], e = rowp[wid + 1];
    for (int p = s; p < e; ++p) {
        int u = col[p];
        unsigned q = *(const unsigned*)(y + (size_t)u * 256 + 128 + lane * 2);
        ax += bf2f(q & 0xffffu); ay += bf2f(q >> 16);
    }
    unsigned r = (unsigned)f2bf(fmaxf(ax, 0.f)) |
                 ((unsigned)f2bf(fmaxf(ay, 0.f)) << 16);
    *(unsigned*)(x + (size_t)wid * 128 + lane * 2) = r;
}

// ---------------------------------------------------------------------------
// Final projection: out[v] = x[v] @ vo_W.T + vo_b  (bf16 x, fp32 out, N=3)
// ---------------------------------------------------------------------------
__global__ __launch_bounds__(256) void vout_kernel(
    const short* __restrict__ x, const float* __restrict__ W,
    const float* __restrict__ b, float* __restrict__ out)
{
    int v = blockIdx.x * blockDim.x + threadIdx.x;
    if (v >= V_N) return;
    const short* xin = x + (size_t)v * 128;
    float a0 = b[0], a1 = b[1], a2 = b[2];
    #pragma unroll
    for (int k0 = 0; k0 < 128; k0 += 8) {
        float4 t = *(const float4*)(xin + k0);
        const unsigned* u = (const unsigned*)&t;
        #pragma unroll
        for (int q = 0; q < 4; ++q) {
            float xl = bf2f(u[q] & 0xffffu), xh = bf2f(u[q] >> 16);
            int k = k0 + q * 2;
            a0 += xl * W[k]       + xh * W[k + 1];
            a1 += xl * W[128 + k] + xh * W[129 + k];
            a2 += xl * W[256 + k] + xh * W[257 + k];
        }
    }
    out[3 * v]     = a0;
    out[3 * v + 1] = a1;
    out[3 * v + 2] = a2;
}

// ------------------------- weight / input prep ----------------------------
__global__ void prep_bn_kernel(const float* __restrict__ W, short* __restrict__ Wb)
{
    int i = blockIdx.x * 256 + threadIdx.x;
    if (i < 128 * FEAT) Wb[i] = (short)f2bf(W[i]);
}

__global__ void prep_w0_kernel(const float* __restrict__ W0, const float* __restrict__ b0,
                               const float* __restrict__ W1, const float* __restrict__ b1,
                               short* __restrict__ Wc, float* __restrict__ bc)
{
    int i = blockIdx.x * 256 + threadIdx.x;
    if (i < 256 * 192) {
        int r = i / 192, c = i % 192;
        float v = 0.f;
        if (c < 131) v = (r < 128) ? W0[r * 131 + c] : W1[(r - 128) * 131 + c];
        Wc[i] = (short)f2bf(v);
    }
    if (i < 256) bc[i] = (i < 128) ? b0[i] : b1[i - 128];
}

__global__ void prep_wl_kernel(const float* __restrict__ gW0, const float* __restrict__ gb0,
                               const float* __restrict__ gW1, const float* __restrict__ gb1,
                               short* __restrict__ Wc, float* __restrict__ bc)
{
    int i = blockIdx.x * 256 + threadIdx.x;
    if (i < NREST * 256 * 128) {
        int l = i / (256 * 128), r = (i / 128) % 256, c = i % 128;
        float v = (r < 128) ? gW0[(l * 128 + r) * 128 + c]
                            : gW1[(l * 128 + (r - 128)) * 128 + c];
        Wc[i] = (short)f2bf(v);
    }
    if (i < NREST * 256) {
        int l = i / 256, r = i % 256;
        bc[i] = (r < 128) ? gb0[l * 128 + r] : gb1[l * 128 + (r - 128)];
    }
}

__global__ void pad_x0_kernel(const float* __restrict__ verts, short* __restrict__ x0)
{
    int v = blockIdx.x * blockDim.x + threadIdx.x;
    if (v >= V_N) return;
    short* row = x0 + (size_t)v * 192;
    row[128] = (short)f2bf(verts[3 * v]);
    row[129] = (short)f2bf(verts[3 * v + 1]);
    row[130] = (short)f2bf(verts[3 * v + 2]);
    #pragma unroll
    for (int c = 131; c < 192; ++c) row[c] = 0;
}

// ------------------------- CSR construction -------------------------------
__global__ void deg_count_kernel(const int* __restrict__ edges, int* __restrict__ deg)
{
    int e = blockIdx.x * blockDim.x + threadIdx.x;
    if (e >= E_N) return;
    int i = edges[2 * e], j = edges[2 * e + 1];
    atomicAdd(&deg[i], 1);
    atomicAdd(&deg[j], 1);
}

__global__ __launch_bounds__(1024) void scan_block_kernel(
    const int* __restrict__ deg, int* __restrict__ excl, int* __restrict__ bsum)
{
    __shared__ int sdata[1024];
    int t = threadIdx.x;
    int base = blockIdx.x * 1024;
    int val = (base + t < V_N) ? deg[base + t] : 0;
    sdata[t] = val; __syncthreads();
    for (int off = 1; off < 1024; off <<= 1) {
        int tmp = (t >= off) ? sdata[t - off] : 0;
        __syncthreads();
        sdata[t] += tmp;
        __syncthreads();
    }
    if (base + t < V_N) excl[base + t] = sdata[t] - val;
    if (t == 1023) bsum[blockIdx.x] = sdata[1023];
}

__global__ __launch_bounds__(256) void scan_bsum_kernel(
    const int* __restrict__ bsum, int* __restrict__ boff)
{
    __shared__ int sdata[256];
    int t = threadIdx.x;
    int val = (t < NSCAN) ? bsum[t] : 0;
    sdata[t] = val; __syncthreads();
    for (int off = 1; off < 256; off <<= 1) {
        int tmp = (t >= off) ? sdata[t - off] : 0;
        __syncthreads();
        sdata[t] += tmp;
        __syncthreads();
    }
    if (t < NSCAN) boff[t] = sdata[t] - val;
    if (t == 255) boff[NSCAN] = sdata[255];
}

__global__ void scan_add_kernel(const int* __restrict__ boff,
                                int* __restrict__ rowp, int* __restrict__ cur)
{
    int i = blockIdx.x * blockDim.x + threadIdx.x;
    if (i < V_N) {
        int r = rowp[i] + boff[i >> 10];
        rowp[i] = r;
        cur[i] = r;
    } else if (i == V_N) {
        rowp[V_N] = boff[NSCAN];
    }
}

__global__ void fill_kernel(const int* __restrict__ edges,
                            int* __restrict__ cur, int* __restrict__ col)
{
    int e = blockIdx.x * blockDim.x + threadIdx.x;
    if (e >= E_N) return;
    int i = edges[2 * e], j = edges[2 * e + 1];
    col[atomicAdd(&cur[i], 1)] = j;
    col[atomicAdd(&cur[j], 1)] = i;
}

// ---------------------------------------------------------------------------
extern "C" void kernel_launch(void* const* d_in, const int* in_sizes, int n_in,
                              void* d_out, int out_size, void* d_ws, size_t ws_size,
                              hipStream_t stream)
{
    const float* img   = (const float*)d_in[0];
    const float* verts = (const float*)d_in[1];
    const int*   edges = (const int*)  d_in[2];
    const float* bnW   = (const float*)d_in[3];
    const float* bnb   = (const float*)d_in[4];
    const float* g0W0  = (const float*)d_in[5];
    const float* g0b0  = (const float*)d_in[6];
    const float* g0W1  = (const float*)d_in[7];
    const float* g0b1  = (const float*)d_in[8];
    const float* gW0   = (const float*)d_in[9];
    const float* gb0   = (const float*)d_in[10];
    const float* gW1   = (const float*)d_in[11];
    const float* gb1   = (const float*)d_in[12];
    const float* voW   = (const float*)d_in[13];
    const float* vob   = (const float*)d_in[14];
    float* out = (float*)d_out;

    // workspace layout (all segment byte counts multiples of 16)
    short* x0   = (short*)d_ws;                       // V*192 bf16
    short* ybuf = x0   + (size_t)V_N * 192;           // V*256 bf16
    short* xbf  = ybuf + (size_t)V_N * 256;           // V*128 bf16
    short* bnWb = xbf  + (size_t)V_N * 128;           // 128*960
    short* Wc0  = bnWb + 128 * FEAT;                  // 256*192
    short* Wcl  = Wc0  + 256 * 192;                   // 7*256*128
    float* bc0  = (float*)(Wcl + NREST * 256 * 128);  // 256
    float* bcl  = bc0  + 256;                         // 7*256
    int*   deg  = (int*)(bcl + NREST * 256);          // V
    int*   rowp = deg  + V_N;                         // V+1
    int*   cur  = rowp + V_N + 1;                     // V
    int*   bsum = cur  + V_N;                         // 256
    int*   boff = bsum + 256;                         // NSCAN+1
    int*   col  = boff + 257;                         // 2E

    // ---- CSR build ----
    hipMemsetAsync(deg, 0, V_N * sizeof(int), stream);
    deg_count_kernel<<<(E_N + 255) / 256, 256, 0, stream>>>(edges, deg);
    scan_block_kernel<<<NSCAN, 1024, 0, stream>>>(deg, rowp, bsum);
    scan_bsum_kernel<<<1, 256, 0, stream>>>(bsum, boff);
    scan_add_kernel<<<(V_N + 256) / 256, 256, 0, stream>>>(boff, rowp, cur);
    fill_kernel<<<(E_N + 255) / 256, 256, 0, stream>>>(edges, cur, col);

    // ---- weight / x0 prep ----
    prep_bn_kernel<<<(128 * FEAT + 255) / 256, 256, 0, stream>>>(bnW, bnWb);
    prep_w0_kernel<<<(256 * 192 + 255) / 256, 256, 0, stream>>>(g0W0, g0b0, g0W1, g0b1, Wc0, bc0);
    prep_wl_kernel<<<(NREST * 256 * 128 + 255) / 256, 256, 0, stream>>>(gW0, gb0, gW1, gb1, Wcl, bcl);
    pad_x0_kernel<<<(V_N + 255) / 256, 256, 0, stream>>>(verts, x0);

    const int MB = (V_N + 127) / 128;   // 1563

    // ---- backbone: img(fp32,K=960) @ bnW^T -> x0 cols 0..127 (relu) ----
    mfma_gemm_kernel<15, true, true><<<dim3(MB, 1), 256, 0, stream>>>(
        img, FEAT, bnWb, FEAT, bnb, x0, 192);

    // ---- layer 0: x0(K=192 padded) @ Wc0^T -> y[V][256] ----
    mfma_gemm_kernel<3, false, false><<<dim3(MB, 2), 256, 0, stream>>>(
        x0, 192, Wc0, 192, bc0, ybuf, 256);
    agg_kernel<<<(V_N * 64 + 255) / 256, 256, 0, stream>>>(ybuf, rowp, col, xbf);

    // ---- layers 1..7 ----
    for (int l = 0; l < NREST; ++l) {
        mfma_gemm_kernel<2, false, false><<<dim3(MB, 2), 256, 0, stream>>>(
            xbf, 128, Wcl + (size_t)l * 256 * 128, 128, bcl + (size_t)l * 256, ybuf, 256);
        agg_kernel<<<(V_N * 64 + 255) / 256, 256, 0, stream>>>(ybuf, rowp, col, xbf);
    }

    // ---- final projection ----
    vout_kernel<<<(V_N + 255) / 256, 256, 0, stream>>>(xbf, voW, vob, out);
}